// Round 9
// baseline (1003.591 us; speedup 1.0000x reference)
//
#include <hip/hip_runtime.h>
#include <hip/hip_cooperative_groups.h>

namespace cg = cooperative_groups;

#define H 128

typedef float v4f __attribute__((ext_vector_type(4)));
typedef short v8s __attribute__((ext_vector_type(8)));

// ---------------- bf16 helpers ----------------

__device__ inline unsigned short bf16_rne(float x) {
  unsigned u = __builtin_bit_cast(unsigned, x);
  unsigned r = u + 0x7FFF + ((u >> 16) & 1);
  return (unsigned short)(r >> 16);
}

__device__ inline void split_bf16(float x, unsigned short& hi, unsigned short& lo) {
  unsigned u = __builtin_bit_cast(unsigned, x);
  unsigned r = u + 0x7FFF + ((u >> 16) & 1);  // RNE round to bf16
  hi = (unsigned short)(r >> 16);
  float hf = __builtin_bit_cast(float, r & 0xFFFF0000u);
  float d = x - hf;
  unsigned ud = __builtin_bit_cast(unsigned, d);
  unsigned rd = ud + 0x7FFF + ((ud >> 16) & 1);
  lo = (unsigned short)(rd >> 16);
}

// Frag-order index for bf16 planes: value (row r, channel k) lives at
//   (r>>4)*2048 + (k>>5)*512 + (((k>>3)&3)*16 + (r&15))*8 + (k&7)
// A wave (q=lane>>4, m=lane&15) reads one 16x32 A-frag as v8s idx
// T*256 + kb*64 + lane (lane m <-> row T*16+m, q <-> channels kb*32+q*8..+7).

// ---------------- fused CSR build (ONE cooperative dispatch) ----------------
// phases: zero deg -> histogram -> chunk sums -> scan chunk sums (block 0)
// -> per-chunk scan (row_start, cursor=row_start) -> fill. grid.sync between.
// 1024 blocks x 256 threads: 4 blocks/CU, trivially co-resident.

__global__ __launch_bounds__(256) void csr_build_kernel(
    const int* __restrict__ src, const int* __restrict__ dst, int* __restrict__ deg,
    int* __restrict__ cursor, int* __restrict__ row_start, int* __restrict__ chunk_sum,
    int* __restrict__ chunk_off, int* __restrict__ csr_src, int N, int E) {
  cg::grid_group g = cg::this_grid();
  int tid = threadIdx.x, bid = blockIdx.x, nb = gridDim.x;
  int gt = bid * 256 + tid, gs = nb * 256;
  __shared__ int lds[512];

  // phase 1: zero deg
  for (int i = gt; i < N; i += gs) deg[i] = 0;
  g.sync();

  // phase 2: histogram
  for (int e = gt; e < E; e += gs) atomicAdd(&deg[dst[e]], 1);
  g.sync();

  // phase 3a: per-chunk (256 elems) sums
  int nch = (N + 255) >> 8;  // <= 512
  for (int c = bid; c < nch; c += nb) {
    int i = c * 256 + tid;
    lds[tid] = (i < N) ? deg[i] : 0;
    __syncthreads();
    for (int off = 128; off > 0; off >>= 1) {
      if (tid < off) lds[tid] += lds[tid + off];
      __syncthreads();
    }
    if (tid == 0) chunk_sum[c] = lds[0];
    __syncthreads();
  }
  g.sync();

  // phase 3b: block 0 scans chunk sums (two 256-halves)
  if (bid == 0) {
    int v0 = (tid < nch) ? chunk_sum[tid] : 0;
    int v1 = (tid + 256 < nch) ? chunk_sum[tid + 256] : 0;
    lds[tid] = v0;
    __syncthreads();
    for (int off = 1; off < 256; off <<= 1) {
      int x = (tid >= off) ? lds[tid - off] : 0;
      __syncthreads();
      lds[tid] += x;
      __syncthreads();
    }
    int incl0 = lds[tid], total0 = lds[255];
    __syncthreads();
    lds[tid] = v1;
    __syncthreads();
    for (int off = 1; off < 256; off <<= 1) {
      int x = (tid >= off) ? lds[tid - off] : 0;
      __syncthreads();
      lds[tid] += x;
      __syncthreads();
    }
    int incl1 = lds[tid] + total0;
    if (tid < nch) chunk_off[tid] = incl0 - v0;
    if (tid + 256 < nch) chunk_off[tid + 256] = incl1 - v1;
  }
  g.sync();

  // phase 3c: per-chunk exclusive scan -> row_start, cursor
  for (int c = bid; c < nch; c += nb) {
    int i = c * 256 + tid;
    int v = (i < N) ? deg[i] : 0;
    lds[tid] = v;
    __syncthreads();
    for (int off = 1; off < 256; off <<= 1) {
      int x = (tid >= off) ? lds[tid - off] : 0;
      __syncthreads();
      lds[tid] += x;
      __syncthreads();
    }
    if (i < N) {
      int rs = chunk_off[c] + lds[tid] - v;
      row_start[i] = rs;
      cursor[i] = rs;
    }
    __syncthreads();
  }
  g.sync();

  // phase 4: fill
  for (int e = gt; e < E; e += gs) {
    int d = dst[e];
    int p = atomicAdd(&cursor[d], 1);
    csr_src[p] = src[e];
  }
}

// ---------------- fused gather + weight pre-split ----------------
// Blocks [0, GB): emb gather -> row-major hb + frag-order hfh/hfl planes.
// Blocks [GB, GB+384): 6x [128x128] W -> frag-order hi/lo planes
//   per plane (16384 shorts): e = c*2048 + kb*512 + q*128 + m*8 + j holds
//   W[col=c*16+m][k=kb*32+q*8+j]; buffer [layer][side][hi,lo][16384].

__global__ void gatherw_kernel(const float* __restrict__ emb, const int* __restrict__ node_id,
                               unsigned short* __restrict__ hb,
                               unsigned short* __restrict__ hfh,
                               unsigned short* __restrict__ hfl,
                               const float* __restrict__ W0, const float* __restrict__ W1,
                               const float* __restrict__ W2, const float* __restrict__ W3,
                               const float* __restrict__ W4, const float* __restrict__ W5,
                               unsigned short* __restrict__ Wf, int N, int GB) {
  if ((int)blockIdx.x < GB) {
    int i = blockIdx.x * 256 + threadIdx.x;
    if (i < N * 32) {
      int n = i >> 5, g = i & 31;  // g: float4 group, channels g*4..g*4+3
      float4 v = ((const float4*)emb)[(size_t)node_id[n] * 32 + g];
      float vv[4] = {v.x, v.y, v.z, v.w};
      unsigned short hs[4], ls[4];
#pragma unroll
      for (int k = 0; k < 4; ++k) split_bf16(vv[k], hs[k], ls[k]);
      *(uint2*)(hb + (size_t)n * H + g * 4) =
          make_uint2((unsigned)hs[0] | ((unsigned)hs[1] << 16),
                     (unsigned)hs[2] | ((unsigned)hs[3] << 16));
      size_t fi = (size_t)(n >> 4) * 2048 + (g >> 3) * 512 +
                  (((g >> 1) & 3) * 16 + (n & 15)) * 8 + (g & 1) * 4;
      *(uint2*)(hfh + fi) = make_uint2((unsigned)hs[0] | ((unsigned)hs[1] << 16),
                                       (unsigned)hs[2] | ((unsigned)hs[3] << 16));
      *(uint2*)(hfl + fi) = make_uint2((unsigned)ls[0] | ((unsigned)ls[1] << 16),
                                       (unsigned)ls[2] | ((unsigned)ls[3] << 16));
    }
  } else {
    int idx = ((int)blockIdx.x - GB) * 256 + threadIdx.x;  // 0..98303
    int sp = idx >> 14;
    int e = idx & 16383;
    const float* srcp = sp == 0 ? W0 : sp == 1 ? W1 : sp == 2 ? W2
                      : sp == 3 ? W3 : sp == 4 ? W4 : W5;
    int c = e >> 11;
    int kb = (e >> 9) & 3;
    int qq = (e >> 7) & 3;
    int mm = (e >> 3) & 15;
    int j = e & 7;
    unsigned short hi, lo;
    split_bf16(srcp[(c * 16 + mm) * H + kb * 32 + qq * 8 + j], hi, lo);
    size_t base = (size_t)(sp >> 1) * 65536 + (size_t)(sp & 1) * 32768 + e;
    Wf[base] = hi;
    Wf[base + 16384] = lo;
  }
}

// ---------------- mean aggregation (CSR; row-major hb in, frag-order ag planes out) ----------------

__global__ __launch_bounds__(256) void aggregate_kernel(const unsigned short* __restrict__ hb,
                                                        const int* __restrict__ csr_src,
                                                        const int* __restrict__ row_start,
                                                        const int* __restrict__ deg,
                                                        unsigned short* __restrict__ a_hi,
                                                        unsigned short* __restrict__ a_lo, int N) {
  int node = blockIdx.x * 4 + (threadIdx.x >> 6);
  if (node >= N) return;
  int lane = threadIdx.x & 63;
  int qe = lane >> 4;  // edge slot 0..3
  int cl = lane & 15;  // channel group: channels cl*8 .. cl*8+7
  const uint4* __restrict__ h16 = (const uint4*)hb;

  int start = row_start[node];
  int d = deg[node];

  float acc[8] = {0.f, 0.f, 0.f, 0.f, 0.f, 0.f, 0.f, 0.f};

  auto accum = [&](uint4 u) {
    unsigned uu[4] = {u.x, u.y, u.z, u.w};
#pragma unroll
    for (int j = 0; j < 4; ++j) {
      acc[2 * j] += __builtin_bit_cast(float, uu[j] << 16);
      acc[2 * j + 1] += __builtin_bit_cast(float, uu[j] & 0xFFFF0000u);
    }
  };

  int e = qe;
  for (; e + 4 < d; e += 8) {
    int s0 = csr_src[start + e];
    int s1 = csr_src[start + e + 4];
    uint4 u0 = h16[(size_t)s0 * 16 + cl];
    uint4 u1 = h16[(size_t)s1 * 16 + cl];
    accum(u0);
    accum(u1);
  }
  for (; e < d; e += 4) {
    int s = csr_src[start + e];
    accum(h16[(size_t)s * 16 + cl]);
  }

#pragma unroll
  for (int j = 0; j < 8; ++j) {
    acc[j] += __shfl_xor(acc[j], 16);
    acc[j] += __shfl_xor(acc[j], 32);
  }

  float inv = 1.0f / fmaxf((float)d, 1.0f);
  if (qe < 2) {
    // lane holds channels k = cl*8 + qe*4 + j (j=0..3) -> frag-order uint2
    unsigned short hs[4], ls[4];
    int b = qe * 4;
#pragma unroll
    for (int j = 0; j < 4; ++j) split_bf16(acc[b + j] * inv, hs[j], ls[j]);
    size_t fi = (size_t)(node >> 4) * 2048 + (cl >> 2) * 512 +
                ((cl & 3) * 16 + (node & 15)) * 8 + qe * 4;
    *(uint2*)(a_hi + fi) = make_uint2((unsigned)hs[0] | ((unsigned)hs[1] << 16),
                                      (unsigned)hs[2] | ((unsigned)hs[3] << 16));
    *(uint2*)(a_lo + fi) = make_uint2((unsigned)ls[0] | ((unsigned)ls[1] << 16),
                                      (unsigned)ls[2] | ((unsigned)ls[3] << 16));
  }
}

// ---------------- frag-streaming MFMA dual-GEMM (r6-measured engine, verbatim) ----------------
// A (both sides, hi/lo) loaded DIRECTLY global->register from frag-order
// planes: 16B/lane contiguous, no staging VALU. W staged once per side into
// 64 KiB static LDS (stride-1 b128 both directions, conflict-free); 4
// barriers per kernel. 256 threads, BM=128 (4 waves x 2 row-tiles).
// In-place h-plane update: each block reads only its own 128 rows before
// its epilogue writes them (proven aliasing class).

template <int RELU, int FINAL>
__global__ __launch_bounds__(256) void gemm_fs(
    const unsigned short* __restrict__ agh, const unsigned short* __restrict__ agl,
    const unsigned short* hfh, const unsigned short* hfl,
    const unsigned short* __restrict__ Wfrag, const float* __restrict__ bias,
    unsigned short* hfh_out, unsigned short* hfl_out, unsigned short* hb_out,
    float* __restrict__ outf, int N) {
  __shared__ __align__(16) unsigned short Wsh[32768];  // 64 KiB: [hi 16384][lo 16384]

  int tid = threadIdx.x;
  int wave = tid >> 6, lane = tid & 63;
  int m = lane & 15, q = lane >> 4;
  int T0 = blockIdx.x * 8 + wave * 2;  // this wave's first row-tile

  v4f acc[16];  // [tr*8 + c]
#pragma unroll
  for (int t = 0; t < 16; ++t) acc[t] = (v4f){0.f, 0.f, 0.f, 0.f};

  for (int side = 0; side < 2; ++side) {
    const v8s* Wg = (const v8s*)(Wfrag + side * 32768);
    const v8s* XH = (const v8s*)(side ? hfh : agh);
    const v8s* XL = (const v8s*)(side ? hfl : agl);

    __syncthreads();  // previous side's W reads complete before overwrite
#pragma unroll
    for (int i = 0; i < 16; ++i) ((v8s*)Wsh)[tid + i * 256] = Wg[tid + i * 256];
    __syncthreads();

    const v8s* WF = (const v8s*)Wsh;
#pragma unroll
    for (int kb = 0; kb < 4; ++kb) {
      v8s ah0 = XH[(size_t)T0 * 256 + kb * 64 + lane];
      v8s ah1 = XH[(size_t)(T0 + 1) * 256 + kb * 64 + lane];
      v8s al0 = XL[(size_t)T0 * 256 + kb * 64 + lane];
      v8s al1 = XL[(size_t)(T0 + 1) * 256 + kb * 64 + lane];
#pragma unroll
      for (int c = 0; c < 8; ++c) {
        v8s bh = WF[c * 256 + kb * 64 + lane];
        v8s bl = WF[2048 + c * 256 + kb * 64 + lane];
        acc[c] = __builtin_amdgcn_mfma_f32_16x16x32_bf16(ah0, bh, acc[c], 0, 0, 0);
        acc[c] = __builtin_amdgcn_mfma_f32_16x16x32_bf16(al0, bh, acc[c], 0, 0, 0);
        acc[c] = __builtin_amdgcn_mfma_f32_16x16x32_bf16(ah0, bl, acc[c], 0, 0, 0);
        acc[8 + c] = __builtin_amdgcn_mfma_f32_16x16x32_bf16(ah1, bh, acc[8 + c], 0, 0, 0);
        acc[8 + c] = __builtin_amdgcn_mfma_f32_16x16x32_bf16(al1, bh, acc[8 + c], 0, 0, 0);
        acc[8 + c] = __builtin_amdgcn_mfma_f32_16x16x32_bf16(ah1, bl, acc[8 + c], 0, 0, 0);
      }
    }
  }

  // --- epilogue: bias + activation; frag-order hi/lo + row-major hb (or fp32 final) ---
  float bv[8];
#pragma unroll
  for (int c = 0; c < 8; ++c) bv[c] = bias[c * 16 + m];
#pragma unroll
  for (int tr = 0; tr < 2; ++tr) {
    int T = T0 + tr;
#pragma unroll
    for (int c = 0; c < 8; ++c) {
      v4f a = acc[tr * 8 + c];
      size_t fb = (size_t)T * 2048 + (c >> 1) * 512 +
                  (((c & 1) * 2 + (m >> 3)) * 16) * 8 + (m & 7);
#pragma unroll
      for (int i = 0; i < 4; ++i) {
        int row = T * 16 + q * 4 + i;
        if (row < N) {
          float v = a[i] + bv[c];
          if (RELU) v = fmaxf(v, 0.f);
          if (FINAL) {
            outf[(size_t)row * H + c * 16 + m] = v;
          } else {
            unsigned short hi, lo;
            split_bf16(v, hi, lo);
            size_t fi = fb + (q * 4 + i) * 8;
            hfh_out[fi] = hi;
            hfl_out[fi] = lo;
            hb_out[(size_t)row * H + c * 16 + m] = hi;  // hb image == hi plane value
          }
        }
      }
    }
  }
}

// ---------------- launch ----------------

extern "C" void kernel_launch(void* const* d_in, const int* in_sizes, int n_in,
                              void* d_out, int out_size, void* d_ws, size_t ws_size,
                              hipStream_t stream) {
  const int* node_id = (const int*)d_in[0];
  const int* edge_index = (const int*)d_in[1];
  const float* emb = (const float*)d_in[2];
  const float* W1l = (const float*)d_in[3];
  const float* b1l = (const float*)d_in[4];
  const float* W1r = (const float*)d_in[5];
  const float* W2l = (const float*)d_in[6];
  const float* b2l = (const float*)d_in[7];
  const float* W2r = (const float*)d_in[8];
  const float* W3l = (const float*)d_in[9];
  const float* b3l = (const float*)d_in[10];
  const float* W3r = (const float*)d_in[11];

  int N = in_sizes[0];
  int E = in_sizes[1] / 2;
  const int* src = edge_index;
  const int* dst = edge_index + E;

  int ggm = (N + 127) / 128;
  size_t Np = (size_t)ggm * 128;  // rows padded to block multiple

  char* w = (char*)d_ws;
  auto alloc = [&](size_t bytes) {
    void* p = (void*)w;
    w += (bytes + 255) & ~(size_t)255;
    return p;
  };
  int* deg = (int*)alloc((size_t)N * 4);
  int* cursor = (int*)alloc((size_t)N * 4);
  int* row_start = (int*)alloc((size_t)N * 4);
  int* chunk_sum = (int*)alloc(2048);
  int* chunk_off = (int*)alloc(2048);
  int* csr_src = (int*)alloc((size_t)E * 4);
  unsigned short* hb = (unsigned short*)alloc(Np * H * 2);   // row-major h hi (bf16)
  unsigned short* hfh = (unsigned short*)alloc(Np * H * 2);  // frag-order h hi
  unsigned short* hfl = (unsigned short*)alloc(Np * H * 2);  // frag-order h lo
  unsigned short* agh = (unsigned short*)alloc(Np * H * 2);  // frag-order aggr hi
  unsigned short* agl = (unsigned short*)alloc(Np * H * 2);  // frag-order aggr lo
  unsigned short* Wf = (unsigned short*)alloc((size_t)3 * 65536 * 2);

  // ---- CSR build: one cooperative dispatch (zero+hist+scan+fill) ----
  {
    void* args[] = {(void*)&src,       (void*)&dst,       (void*)&deg,
                    (void*)&cursor,    (void*)&row_start, (void*)&chunk_sum,
                    (void*)&chunk_off, (void*)&csr_src,   (void*)&N, (void*)&E};
    hipLaunchCooperativeKernel((void*)csr_build_kernel, dim3(1024), dim3(256), args, 0,
                               stream);
  }

  int GB = (N * 32 + 255) / 256;
  gatherw_kernel<<<GB + 384, 256, 0, stream>>>(emb, node_id, hb, hfh, hfl,
                                               W1l, W1r, W2l, W2r, W3l, W3r, Wf, N, GB);

  int gag = (N + 3) / 4;

  // layer 1
  aggregate_kernel<<<gag, 256, 0, stream>>>(hb, csr_src, row_start, deg, agh, agl, N);
  gemm_fs<1, 0><<<ggm, 256, 0, stream>>>(agh, agl, hfh, hfl, Wf + 0 * 65536, b1l,
                                         hfh, hfl, hb, nullptr, N);

  // layer 2
  aggregate_kernel<<<gag, 256, 0, stream>>>(hb, csr_src, row_start, deg, agh, agl, N);
  gemm_fs<1, 0><<<ggm, 256, 0, stream>>>(agh, agl, hfh, hfl, Wf + 1 * 65536, b2l,
                                         hfh, hfl, hb, nullptr, N);

  // layer 3 -> fp32 d_out
  aggregate_kernel<<<gag, 256, 0, stream>>>(hb, csr_src, row_start, deg, agh, agl, N);
  gemm_fs<0, 1><<<ggm, 256, 0, stream>>>(agh, agl, hfh, hfl, Wf + 2 * 65536, b3l,
                                         nullptr, nullptr, nullptr, (float*)d_out, N);
}